// Round 6
// baseline (362.677 us; speedup 1.0000x reference)
//
#include <hip/hip_runtime.h>
#include <cstdint>
#include <cstddef>

typedef unsigned short u16;
typedef __attribute__((ext_vector_type(8))) short bf16x8;
typedef __attribute__((ext_vector_type(4))) float f32x4;

// ---------- bf16 helpers ----------
__device__ __forceinline__ float b2f(u16 u) {
  union { uint32_t i; float f; } x; x.i = ((uint32_t)u) << 16; return x.f;
}
__device__ __forceinline__ u16 f2b(float f) {
  union { float f; uint32_t i; } x; x.f = f;
  uint32_t u = x.i;
  u += 0x7fffu + ((u >> 16) & 1u);   // RNE
  return (u16)(u >> 16);
}
__device__ __forceinline__ void load8(const void* p, size_t idx, bool f32, float o[8]) {
  if (f32) {
    const float4* fp = (const float4*)((const float*)p + idx);
    float4 x = fp[0], y = fp[1];
    o[0] = x.x; o[1] = x.y; o[2] = x.z; o[3] = x.w;
    o[4] = y.x; o[5] = y.y; o[6] = y.z; o[7] = y.w;
  } else {
    uint4 w = *(const uint4*)((const u16*)p + idx);
    uint32_t ww[4] = {w.x, w.y, w.z, w.w};
#pragma unroll
    for (int q = 0; q < 4; q++) {
      o[2 * q]     = b2f((u16)(ww[q] & 0xffffu));
      o[2 * q + 1] = b2f((u16)(ww[q] >> 16));
    }
  }
}
__device__ __forceinline__ void store8_bf16(u16* p, size_t idx, const float o[8]) {
  uint32_t w[4];
#pragma unroll
  for (int q = 0; q < 4; q++)
    w[q] = (uint32_t)f2b(o[2 * q]) | ((uint32_t)f2b(o[2 * q + 1]) << 16);
  *(uint4*)(p + idx) = make_uint4(w[0], w[1], w[2], w[3]);
}

// per-block dtype detect (bf16 vs f32) from raw bits of l; broadcast via LDS.
__device__ __forceinline__ bool detect_f32(const u16* lb, int* ldsflag, int tid) {
  if (tid < 64) {
    int bad = 0;
    for (int i = tid; i < 1024; i += 64) {
      float f = b2f(lb[i]);
      if (!(fabsf(f) <= 1.0e4f)) bad = 1;   // catches NaN too
    }
    int any = __any(bad);
    if (tid == 0) *ldsflag = any;
  }
  __syncthreads();
  const bool r = (*ldsflag != 0);
  __syncthreads();
  return r;
}

// ================= fragment-major layouts =================
// A-frag (featsF/aggF/gbF, bf16): elem (row, k) lives at
//   chunk = (row>>4)*16 + (k>>5)                       [960 x 16 chunks]
//   off   = chunk*512 + (((k>>3)&3)*16 + (row&15))*8 + (k&7)
// A wave's af fragment (rb, kb) is then base + lane*8 -> one coalesced 1KB load
// per fragment (lane = quad*16 + l16: row = rb*16+l16, k = kb*32+quad*8+e).
// B-frag (WtF) identical with row->col n.
// gF (f32 resid) is acc-native: frag (rb, cb): gF[((rb*32+cb)*64 + lane)*4..+4]
// = rows rb*16+quad*4..+4, col cb*16+l16 -> 16B/lane, no transpose ever.

// ---------- weight transpose -> frag-major WtF ----------
__global__ __launch_bounds__(1024)
void transw_k(const void* __restrict__ fc1W, const void* __restrict__ convW,
              const u16* __restrict__ lbits, u16* __restrict__ WtF)
{
  __shared__ u16 tile[32][33];
  __shared__ int flagS;
  const int tx = threadIdx.x, ty = threadIdx.y;
  const int tid = ty * 32 + tx;
  const bool f32 = detect_f32(lbits, &flagS, tid);
  const int w = blockIdx.z;
  const void* W = (w == 0) ? fc1W : convW;
  const size_t base = (w == 0) ? 0 : (size_t)(w - 1) * 262144;
  const int bx = blockIdx.x, by = blockIdx.y;
  const size_t i = base + (size_t)(by * 32 + ty) * 512 + (bx * 32 + tx);
  float val = f32 ? ((const float*)W)[i] : b2f(((const u16*)W)[i]);
  tile[ty][tx] = f2b(val);   // tile[ty][tx] = W[by*32+ty][bx*32+tx]
  __syncthreads();
  // output: n = bx*32 + nbp*16 + l16 ; k = by*32 + q*8 + e ; value = W[k][n]
  const int e = tid & 7, l16 = (tid >> 3) & 15, q = (tid >> 7) & 3, nbp = tid >> 9;
  const u16 vv = tile[q * 8 + e][nbp * 16 + l16];
  WtF[(size_t)w * 262144 + ((size_t)((bx * 2 + nbp) * 16 + by)) * 512 +
      (q * 16 + l16) * 8 + e] = vv;
}

// ---------- feats -> frag-major featsF + d_out cols [0,512) ----------
// wave <-> 16-row block rb; lane = (q,l16): row = rb*16+l16, cols kb*32+q*8..+8
__global__ __launch_bounds__(256)
void featfrag_k(const void* __restrict__ a, const void* __restrict__ v,
                const void* __restrict__ l, const void* __restrict__ qmask,
                const void* __restrict__ spk,
                u16* __restrict__ featsF, void* __restrict__ outv)
{
  __shared__ int flagS;
  const int tid = threadIdx.x;
  const bool f32io = detect_f32((const u16*)l, &flagS, tid);
  const int wave = tid >> 6, lane = tid & 63;
  const int q = lane >> 4, l16 = lane & 15;
  const int rb = blockIdx.x * 4 + wave;          // 0..959
  const int row = rb * 16 + l16;
  const int dm = row / 40, t = row - dm * 40;
  const int mod = dm % 3, d = dm / 3, u = d * 40 + t;
  const void* srcp = (mod == 1) ? a : ((mod == 2) ? v : l);
  const bool addspk = (mod == 0);
  size_t spkOff = 0;
  if (addspk) {
    const int qi = (t * 128 + d) * 2;
    float q0 = f32io ? ((const float*)qmask)[qi]     : b2f(((const u16*)qmask)[qi]);
    float q1 = f32io ? ((const float*)qmask)[qi + 1] : b2f(((const u16*)qmask)[qi + 1]);
    spkOff = (q1 > q0) ? 512 : 0;                // np.argmax tie -> first index
  }
#pragma unroll
  for (int kb = 0; kb < 16; ++kb) {
    const int c0 = kb * 32 + q * 8;
    float vals[8];
    load8(srcp, (size_t)u * 512 + c0, f32io, vals);
    if (addspk) {
      float sv[8];
      load8(spk, spkOff + c0, f32io, sv);
#pragma unroll
      for (int j = 0; j < 8; ++j) vals[j] += sv[j];
    }
    const size_t oidx = (size_t)u * 4608 + (size_t)mod * 1536 + c0;
    if (f32io) {
      float4* op = (float4*)((float*)outv + oidx);
      op[0] = make_float4(vals[0], vals[1], vals[2], vals[3]);
      op[1] = make_float4(vals[4], vals[5], vals[6], vals[7]);
    } else {
      store8_bf16((u16*)outv, oidx, vals);
    }
    uint32_t w[4];
#pragma unroll
    for (int p = 0; p < 4; ++p)
      w[p] = (uint32_t)f2b(vals[2 * p]) | ((uint32_t)f2b(vals[2 * p + 1]) << 16);
    *(uint4*)(featsF + (((size_t)(rb * 16 + kb)) << 9) + (size_t)lane * 8) =
        make_uint4(w[0], w[1], w[2], w[3]);
  }
}

// ---------- agg: gbF (frag) -> aggF (frag), colsum fused ----------
// block = (dialogue d, col-half): phase1 colsum (t-ascending, bit-identical),
// phase2 agg chunks. All frag-chunk reads/writes are 16B coalesced.
__global__ __launch_bounds__(256)
void agg_k(const u16* __restrict__ gbF, u16* __restrict__ aggF)
{
  __shared__ __align__(16) float Bs[3][256];
  const int tid = threadIdx.x;
  const int d = blockIdx.x >> 1, half = blockIdx.x & 1;
  const int base = d * 120;
  // phase 1: column sums, col c = half*256 + tid
  {
    const int c = half * 256 + tid;
    const int ckb = c >> 5, cq = (c >> 3) & 3, ce = c & 7;
#pragma unroll
    for (int m = 0; m < 3; ++m) {
      float s = 0.f;
#pragma unroll 8
      for (int t = 0; t < 40; ++t) {
        const int row = base + m * 40 + t;
        s += b2f(gbF[(((size_t)((row >> 4) * 16 + ckb)) << 9) +
                     (cq * 16 + (row & 15)) * 8 + ce]);
      }
      Bs[m][tid] = s;
    }
  }
  __syncthreads();
  // phase 2: agg chunks
  const int wave = tid >> 6, lane = tid & 63;
  const int q = lane >> 4, l16 = lane & 15;
  const int rb0 = base >> 4;
  const float inv42 = 1.0f / 42.0f;
#pragma unroll
  for (int it = 0; it < 16; ++it) {
    const int task = it * 4 + wave;       // 64 tasks: (rbi 8) x (kbi 8)
    const int rbi = task >> 3, kbi = task & 7;
    const int rb = rb0 + rbi, kb = half * 8 + kbi;
    const int row = rb * 16 + l16, rel = row - base;
    if (rel >= 0 && rel < 120) {
      const int mod = rel / 40, tt = rel - mod * 40;
      const int m1 = (mod == 0) ? 1 : 0;
      const int m2 = (mod == 2) ? 1 : 2;
      const int n1 = base + m1 * 40 + tt;
      const int n2 = base + m2 * 40 + tt;
      uint4 x1 = *(const uint4*)(gbF + (((size_t)((n1 >> 4) * 16 + kb)) << 9) +
                                 (q * 16 + (n1 & 15)) * 8);
      uint4 x2 = *(const uint4*)(gbF + (((size_t)((n2 >> 4) * 16 + kb)) << 9) +
                                 (q * 16 + (n2 & 15)) * 8);
      const float* bp = &Bs[mod][kbi * 32 + q * 8];
      float4 b0 = *(const float4*)bp, b1 = *(const float4*)(bp + 4);
      const float bs_[8] = {b0.x, b0.y, b0.z, b0.w, b1.x, b1.y, b1.z, b1.w};
      uint32_t w1[4] = {x1.x, x1.y, x1.z, x1.w};
      uint32_t w2[4] = {x2.x, x2.y, x2.z, x2.w};
      float o[8];
#pragma unroll
      for (int p = 0; p < 4; ++p) {
        o[2*p]   = (bs_[2*p]   + b2f((u16)(w1[p] & 0xffffu)) + b2f((u16)(w2[p] & 0xffffu))) * inv42;
        o[2*p+1] = (bs_[2*p+1] + b2f((u16)(w1[p] >> 16))     + b2f((u16)(w2[p] >> 16)))     * inv42;
      }
      uint32_t w[4];
#pragma unroll
      for (int p = 0; p < 4; ++p)
        w[p] = (uint32_t)f2b(o[2 * p]) | ((uint32_t)f2b(o[2 * p + 1]) << 16);
      *(uint4*)(aggF + (((size_t)(rb * 16 + kb)) << 9) + (size_t)lane * 8) =
          make_uint4(w[0], w[1], w[2], w[3]);
    }
  }
}

// ---------- GEMM v6: barrier-free fragment GEMM ----------
// 256 thr = 4 independent waves; wave tile 64x64 (acc[4][4] f32x4); A and B read
// directly from frag-major global (1KB coalesced per fragment). NO LDS staging,
// NO barriers in the K-loop. 2-stage register prefetch -> counted vmcnt.
// Epilogue: gF (resid) in acc-native frag layout (16B/lane, no transpose);
// gbF + linear d_out rows via wave-private LDS transpose (lgkmcnt only).
#define LOADCH(AF, BV, KB)                                                      \
  _Pragma("unroll") for (int i_ = 0; i_ < 4; ++i_)                              \
    AF[i_] = *(const bf16x8*)(Af + (((size_t)((mt4 + i_) * 16 + (KB))) << 9) + lane8); \
  _Pragma("unroll") for (int j_ = 0; j_ < 4; ++j_)                              \
    BV[j_] = *(const bf16x8*)(Wf + (((size_t)((nt4 + j_) * 16 + (KB))) << 9) + lane8);

#define MFMA16(AF, BV)                                                          \
  __builtin_amdgcn_s_setprio(1);                                                \
  _Pragma("unroll") for (int i_ = 0; i_ < 4; ++i_)                              \
  _Pragma("unroll") for (int j_ = 0; j_ < 4; ++j_)                              \
    acc[i_][j_] = __builtin_amdgcn_mfma_f32_16x16x32_bf16(AF[i_], BV[j_],       \
                                                          acc[i_][j_], 0, 0, 0);\
  __builtin_amdgcn_s_setprio(0);

__global__ __launch_bounds__(256)
void gemm_fr(const u16* __restrict__ Af, const u16* __restrict__ Wf,
             const void* __restrict__ bias, int boff,
             const float* __restrict__ resid,
             float* __restrict__ gFout, u16* __restrict__ gbFout,
             void* __restrict__ outv, int outoff,
             const u16* __restrict__ lbits)
{
  __shared__ __align__(16) float scr[4][1024];   // 4KB per wave (16 cols x 64 rows)
  __shared__ int flagS;
  const int tid = threadIdx.x;
  const bool f32io = detect_f32(lbits, &flagS, tid);
  const int wave = tid >> 6, lane = tid & 63;
  const int q = lane >> 4, l16 = lane & 15;
  const int gw = blockIdx.x * 4 + wave;          // 0..1919
  const int mt = gw >> 3, nt = gw & 7;           // 64-row, 64-col wave tile
  const int mt4 = mt * 4, nt4 = nt * 4;
  const size_t lane8 = (size_t)lane * 8;

  f32x4 acc[4][4];
#pragma unroll
  for (int i = 0; i < 4; ++i)
#pragma unroll
    for (int j = 0; j < 4; ++j) {
      f32x4 z = {0.f, 0.f, 0.f, 0.f};
      acc[i][j] = z;
    }

  bf16x8 afA[4], bvA[4], afB[4], bvB[4];
  LOADCH(afA, bvA, 0);
#pragma unroll
  for (int kb = 0; kb < 16; kb += 2) {
    LOADCH(afB, bvB, kb + 1);
    MFMA16(afA, bvA);
    if (kb + 2 < 16) { LOADCH(afA, bvA, kb + 2); }
    MFMA16(afB, bvB);
  }

  // ---------------- epilogue ----------------
  float* S = scr[wave];
  const bool needT = (gbFout != nullptr) || (outoff >= 0);
  const int rr = lane;                   // transpose-readout row 0..63
  // d_out row mapping for this lane (used when outoff>=0)
  const int gr = mt * 64 + rr;
  const int dd = gr / 120, md = gr - dd * 120, mm = md / 40, tt2 = md - mm * 40;
#pragma unroll
  for (int j = 0; j < 4; ++j) {
    const int col = nt * 64 + j * 16 + l16;
    const float bv_ = f32io ? ((const float*)bias)[boff + col]
                            : b2f(((const u16*)bias)[boff + col]);
#pragma unroll
    for (int i = 0; i < 4; ++i) {
      f32x4 vs = acc[i][j];
      vs[0] += bv_; vs[1] += bv_; vs[2] += bv_; vs[3] += bv_;
      const size_t fidx = (((size_t)(mt4 + i) * 32 + (nt4 + j)) * 64 + lane) * 4;
      if (resid != nullptr) {
        float4 rv = *(const float4*)(resid + fidx);
        vs[0] += rv.x; vs[1] += rv.y; vs[2] += rv.z; vs[3] += rv.w;
      }
      if (gFout != nullptr)
        *(float4*)(gFout + fidx) = make_float4(vs[0], vs[1], vs[2], vs[3]);
      if (needT) {
        const int r0 = i * 16 + q * 4;
        const int xr = r0 ^ ((l16 & 7) << 3);
        *(f32x4*)&S[l16 * 64 + xr] = vs;
      }
    }
    if (needT) {
      asm volatile("s_waitcnt lgkmcnt(0)" ::: "memory");
      float ov[16];
#pragma unroll
      for (int c = 0; c < 16; ++c)
        ov[c] = S[c * 64 + (rr ^ ((c & 7) << 3))];
      if (gbFout != nullptr) {
        const int rb = mt4 + (rr >> 4), l16r = rr & 15;
        const int kb = nt * 2 + (j >> 1), q0 = (j & 1) * 2;
        u16* b0p = gbFout + (((size_t)(rb * 16 + kb)) << 9) + (q0 * 16 + l16r) * 8;
        store8_bf16(b0p, 0, &ov[0]);
        store8_bf16(b0p, 128, &ov[8]);
      }
      if (outoff >= 0) {
        const size_t ob = (size_t)(dd * 40 + tt2) * 4608 + (size_t)mm * 1536 +
                          outoff + nt * 64 + j * 16;
        if (f32io) {
          float* op = (float*)outv + ob;
          *(float4*)op        = make_float4(ov[0],  ov[1],  ov[2],  ov[3]);
          *(float4*)(op + 4)  = make_float4(ov[4],  ov[5],  ov[6],  ov[7]);
          *(float4*)(op + 8)  = make_float4(ov[8],  ov[9],  ov[10], ov[11]);
          *(float4*)(op + 12) = make_float4(ov[12], ov[13], ov[14], ov[15]);
        } else {
          store8_bf16((u16*)outv, ob, &ov[0]);
          store8_bf16((u16*)outv, ob + 8, &ov[8]);
        }
      }
      asm volatile("s_waitcnt lgkmcnt(0)" ::: "memory");   // WAR before next j
    }
  }
}

// ---------- launch ----------
extern "C" void kernel_launch(void* const* d_in, const int* in_sizes, int n_in,
                              void* d_out, int out_size, void* d_ws, size_t ws_size,
                              hipStream_t stream)
{
  const void* a     = d_in[0];
  const void* v     = d_in[1];
  const void* l     = d_in[2];
  const void* qmask = d_in[3];
  const void* spk   = d_in[4];
  const void* fc1W  = d_in[5];
  const void* fc1b  = d_in[6];
  const void* convW = d_in[7];
  const void* convb = d_in[8];

  char* ws = (char*)d_ws;
  u16*   WtF    = (u16*)(ws);                    // 5*512*512*2 =  2,621,440 B
  u16*   featsF = (u16*)(ws + 2621440);          // 15360*512*2 = 15,728,640 B
  float* gF     = (float*)(ws + 18350080);       // 15360*512*4 = 31,457,280 B
  u16*   gbF    = (u16*)(ws + 49807360);         // 15360*512*2 = 15,728,640 B
  u16*   aggF   = (u16*)(ws + 65536000);         // 15360*512*2 = 15,728,640 B
  const u16* lb = (const u16*)l;                 // total ~81.3 MB

  // 1) weights -> frag-major WtF
  transw_k<<<dim3(16, 16, 5), dim3(32, 32), 0, stream>>>(fc1W, convW, lb, WtF);

  // 2) feats -> frag-major featsF + d_out cols [0,512)
  featfrag_k<<<240, 256, 0, stream>>>(a, v, l, qmask, spk, featsF, d_out);

  // 3) layer 0: x1 = feats @ fc1W + fc1b -> gF (frag f32), gbF (frag bf16),
  //    d_out cols [512,1024)
  gemm_fr<<<480, 256, 0, stream>>>(featsF, WtF, fc1b, 0, nullptr,
                                   gF, gbF, d_out, 512, lb);

  // 4) four GCN layers: gF += agg(gbF) @ Wk + bk
  for (int k = 0; k < 4; ++k) {
    agg_k<<<256, 256, 0, stream>>>(gbF, aggF);
    const bool last = (k == 3);
    gemm_fr<<<480, 256, 0, stream>>>(aggF, WtF + (size_t)(k + 1) * 262144,
                                     convb, k * 512, gF,
                                     last ? nullptr : gF,
                                     last ? nullptr : gbF,
                                     last ? d_out : nullptr, last ? 1024 : -1, lb);
  }
}

// Round 7
// 271.250 us; speedup vs baseline: 1.3371x; 1.3371x over previous
//
#include <hip/hip_runtime.h>
#include <cstdint>
#include <cstddef>

typedef unsigned short u16;
typedef __attribute__((ext_vector_type(8))) short bf16x8;
typedef __attribute__((ext_vector_type(4))) float f32x4;

// ---------- bf16 helpers ----------
__device__ __forceinline__ float b2f(u16 u) {
  union { uint32_t i; float f; } x; x.i = ((uint32_t)u) << 16; return x.f;
}
__device__ __forceinline__ u16 f2b(float f) {
  union { float f; uint32_t i; } x; x.f = f;
  uint32_t u = x.i;
  u += 0x7fffu + ((u >> 16) & 1u);   // RNE
  return (u16)(u >> 16);
}
__device__ __forceinline__ void load8(const void* p, size_t idx, bool f32, float o[8]) {
  if (f32) {
    const float4* fp = (const float4*)((const float*)p + idx);
    float4 x = fp[0], y = fp[1];
    o[0] = x.x; o[1] = x.y; o[2] = x.z; o[3] = x.w;
    o[4] = y.x; o[5] = y.y; o[6] = y.z; o[7] = y.w;
  } else {
    uint4 w = *(const uint4*)((const u16*)p + idx);
    uint32_t ww[4] = {w.x, w.y, w.z, w.w};
#pragma unroll
    for (int q = 0; q < 4; q++) {
      o[2 * q]     = b2f((u16)(ww[q] & 0xffffu));
      o[2 * q + 1] = b2f((u16)(ww[q] >> 16));
    }
  }
}
__device__ __forceinline__ void store8_bf16(u16* p, size_t idx, const float o[8]) {
  uint32_t w[4];
#pragma unroll
  for (int q = 0; q < 4; q++)
    w[q] = (uint32_t)f2b(o[2 * q]) | ((uint32_t)f2b(o[2 * q + 1]) << 16);
  *(uint4*)(p + idx) = make_uint4(w[0], w[1], w[2], w[3]);
}

// per-block dtype detect (bf16 vs f32) from raw bits of l; broadcast via LDS.
__device__ __forceinline__ bool detect_f32(const u16* lb, int* ldsflag, int tid) {
  if (tid < 64) {
    int bad = 0;
    for (int i = tid; i < 1024; i += 64) {
      float f = b2f(lb[i]);
      if (!(fabsf(f) <= 1.0e4f)) bad = 1;   // catches NaN too
    }
    int any = __any(bad);
    if (tid == 0) *ldsflag = any;
  }
  __syncthreads();
  const bool r = (*ldsflag != 0);
  __syncthreads();
  return r;
}

// ================= fragment-major layouts (as r6, verified passing) =========
// elem (row, k): chunk = (row>>4)*16 + (k>>5); off_u16 = chunk*512 +
//   (((k>>3)&3)*16 + (row&15))*8 + (k&7).
// A wave's fragment (rb, kb) = base + lane*8 -> one coalesced 16B/lane access
// (lane = q*16+l16 : row = rb*16+l16, k = kb*32+q*8+e). Same for W with n.

// ---------- weight transpose -> frag-major WtF (verbatim from r6) ----------
__global__ __launch_bounds__(1024)
void transw_k(const void* __restrict__ fc1W, const void* __restrict__ convW,
              const u16* __restrict__ lbits, u16* __restrict__ WtF)
{
  __shared__ u16 tile[32][33];
  __shared__ int flagS;
  const int tx = threadIdx.x, ty = threadIdx.y;
  const int tid = ty * 32 + tx;
  const bool f32 = detect_f32(lbits, &flagS, tid);
  const int w = blockIdx.z;
  const void* W = (w == 0) ? fc1W : convW;
  const size_t base = (w == 0) ? 0 : (size_t)(w - 1) * 262144;
  const int bx = blockIdx.x, by = blockIdx.y;
  const size_t i = base + (size_t)(by * 32 + ty) * 512 + (bx * 32 + tx);
  float val = f32 ? ((const float*)W)[i] : b2f(((const u16*)W)[i]);
  tile[ty][tx] = f2b(val);   // tile[ty][tx] = W[by*32+ty][bx*32+tx]
  __syncthreads();
  // output: n = bx*32 + nbp*16 + l16 ; k = by*32 + q*8 + e ; value = W[k][n]
  const int e = tid & 7, l16 = (tid >> 3) & 15, q = (tid >> 7) & 3, nbp = tid >> 9;
  const u16 vv = tile[q * 8 + e][nbp * 16 + l16];
  WtF[(size_t)w * 262144 + ((size_t)((bx * 2 + nbp) * 16 + by)) * 512 +
      (q * 16 + l16) * 8 + e] = vv;
}

// ---------- persistent per-dialogue fused kernel ----------
// 128 blocks (1/dialogue) x 512 thr (8 waves). X (120x512 bf16 + zeroed pad rows
// 120-127) lives in LDS frag-major for the whole kernel (131072 B). Wave w owns
// output cols [w*64, w*64+64): acc[8][4] f32x4 = running residual g (never spilled
// to global). W fragments are read straight from global (L2-resident, 1KB/frag
// coalesced, 1-deep prefetch) -> ZERO barriers inside the K-loop. gb-write +
// colsum + agg are column-local per wave -> exactly one barrier pair per layer.

__device__ __forceinline__ void gemm_layer(f32x4 (&acc)[8][4], const u16* Xs,
                                           const u16* __restrict__ WL,
                                           int nt, int lane)
{
  const int lane8 = lane * 8;
  bf16x8 cw[4], nw[4];
#pragma unroll
  for (int nb = 0; nb < 4; ++nb)
    cw[nb] = *(const bf16x8*)(WL + (((nt * 4 + nb) * 16) << 9) + lane8);
#pragma unroll 2
  for (int kb = 0; kb < 16; ++kb) {
    if (kb < 15) {
#pragma unroll
      for (int nb = 0; nb < 4; ++nb)
        nw[nb] = *(const bf16x8*)(WL + (((nt * 4 + nb) * 16 + kb + 1) << 9) + lane8);
    }
    bf16x8 af[4];
#pragma unroll
    for (int rb = 0; rb < 4; ++rb)
      af[rb] = *(const bf16x8*)&Xs[((rb * 16 + kb) << 9) + lane8];
    __builtin_amdgcn_s_setprio(1);
#pragma unroll
    for (int rb = 0; rb < 4; ++rb)
#pragma unroll
      for (int nb = 0; nb < 4; ++nb)
        acc[rb][nb] = __builtin_amdgcn_mfma_f32_16x16x32_bf16(af[rb], cw[nb],
                                                              acc[rb][nb], 0, 0, 0);
    __builtin_amdgcn_s_setprio(0);
#pragma unroll
    for (int rb = 4; rb < 8; ++rb)
      af[rb - 4] = *(const bf16x8*)&Xs[((rb * 16 + kb) << 9) + lane8];
    __builtin_amdgcn_s_setprio(1);
#pragma unroll
    for (int rb = 4; rb < 8; ++rb)
#pragma unroll
      for (int nb = 0; nb < 4; ++nb)
        acc[rb][nb] = __builtin_amdgcn_mfma_f32_16x16x32_bf16(af[rb - 4], cw[nb],
                                                              acc[rb][nb], 0, 0, 0);
    __builtin_amdgcn_s_setprio(0);
#pragma unroll
    for (int nb = 0; nb < 4; ++nb) cw[nb] = nw[nb];
  }
}

__device__ __forceinline__ void bias_add(f32x4 (&acc)[8][4], const void* bptr,
                                         int boff, bool f32io, int nt, int l16)
{
#pragma unroll
  for (int nb = 0; nb < 4; ++nb) {
    const int col = nt * 64 + nb * 16 + l16;
    const float b = f32io ? ((const float*)bptr)[boff + col]
                          : b2f(((const u16*)bptr)[boff + col]);
#pragma unroll
    for (int rb = 0; rb < 8; ++rb)
#pragma unroll
      for (int r = 0; r < 4; ++r) acc[rb][nb][r] += b;
  }
}

__device__ __forceinline__ void writeout(void* outv, const f32x4 (&acc)[8][4],
                                         int d, int cbase, bool f32io,
                                         int nt, int quad, int l16)
{
#pragma unroll
  for (int rb = 0; rb < 8; ++rb)
#pragma unroll
    for (int r = 0; r < 4; ++r) {
      const int row = rb * 16 + quad * 4 + r;
      if (row < 120) {
        const int mod = row / 40, t = row - mod * 40;
        const size_t base = (size_t)(d * 40 + t) * 4608 + (size_t)mod * 1536 + cbase;
#pragma unroll
        for (int nb = 0; nb < 4; ++nb) {
          const int col = nt * 64 + nb * 16 + l16;
          if (f32io) ((float*)outv)[base + col] = acc[rb][nb][r];
          else       ((u16*)outv)[base + col]  = f2b(acc[rb][nb][r]);
        }
      }
    }
}

// gb = f2b(acc) into this wave's 64 cols of X, then colsum (t-ascending) + agg
// in place -- entirely column-local to the wave, no cross-wave sync needed.
__device__ __forceinline__ void gb_agg(const f32x4 (&acc)[8][4], u16* Xs,
                                       int nt, int lane, int quad, int l16)
{
#pragma unroll
  for (int nb = 0; nb < 4; ++nb) {
    const int c = nt * 64 + nb * 16 + l16;
    const int kc = c >> 5, cq = (c >> 3) & 3, e = c & 7;
#pragma unroll
    for (int rb = 0; rb < 8; ++rb)
#pragma unroll
      for (int r = 0; r < 4; ++r) {
        const int row = rb * 16 + quad * 4 + r;
        if (row < 120)
          Xs[((rb * 16 + kc) << 9) + (cq * 16 + (row & 15)) * 8 + e] =
              f2b(acc[rb][nb][r]);
      }
  }
  asm volatile("s_waitcnt lgkmcnt(0)" ::: "memory");   // writes -> reads below
  const int c = nt * 64 + lane;                        // lane-private column
  const int kc = c >> 5, cq = (c >> 3) & 3, e = c & 7;
  float bs[3];
#pragma unroll
  for (int m = 0; m < 3; ++m) {
    float s = 0.f;
#pragma unroll 8
    for (int t = 0; t < 40; ++t) {
      const int row = m * 40 + t;
      s += b2f(Xs[(((row >> 4) * 16 + kc) << 9) + (cq * 16 + (row & 15)) * 8 + e]);
    }
    bs[m] = s;
  }
  const float inv42 = 1.0f / 42.0f;
#pragma unroll 4
  for (int t = 0; t < 40; ++t) {
    const int r0 = t, r1 = 40 + t, r2 = 80 + t;
    const int i0 = (((r0 >> 4) * 16 + kc) << 9) + (cq * 16 + (r0 & 15)) * 8 + e;
    const int i1 = (((r1 >> 4) * 16 + kc) << 9) + (cq * 16 + (r1 & 15)) * 8 + e;
    const int i2 = (((r2 >> 4) * 16 + kc) << 9) + (cq * 16 + (r2 & 15)) * 8 + e;
    const float x0 = b2f(Xs[i0]), x1 = b2f(Xs[i1]), x2 = b2f(Xs[i2]);
    Xs[i0] = f2b((bs[0] + x1 + x2) * inv42);
    Xs[i1] = f2b((bs[1] + x0 + x2) * inv42);
    Xs[i2] = f2b((bs[2] + x0 + x1) * inv42);
  }
}

__global__ __launch_bounds__(512, 2)
void fused_k(const void* __restrict__ a, const void* __restrict__ v,
             const void* __restrict__ l, const void* __restrict__ qmask,
             const void* __restrict__ spk, const void* __restrict__ fc1b,
             const void* __restrict__ convb, const u16* __restrict__ WtF,
             void* __restrict__ outv)
{
  __shared__ __align__(16) u16 Xs[65536];   // 131072 B, frag-major X
  __shared__ int flagS;
  const int tid = threadIdx.x;
  const bool f32io = detect_f32((const u16*)l, &flagS, tid);
  const int d = blockIdx.x;
  const int lane = tid & 63, nt = tid >> 6;
  const int quad = lane >> 4, l16 = lane & 15;

  // ---- feats phase: inputs -> d_out cols [0,512) + X (bf16 frag) ----
  {
    const int cs = (tid & 63) * 8;
    const int rg = tid >> 6;
    const int kc = cs >> 5, cq = (cs >> 3) & 3;
#pragma unroll
    for (int it = 0; it < 15; ++it) {
      const int r = it * 8 + rg;            // 0..119
      const int mod = r / 40, t = r - mod * 40;
      const int u = d * 40 + t;
      float vals[8];
      const void* srcp = (mod == 1) ? a : ((mod == 2) ? v : l);
      load8(srcp, (size_t)u * 512 + cs, f32io, vals);
      if (mod == 0) {
        const int qi = (t * 128 + d) * 2;
        float q0 = f32io ? ((const float*)qmask)[qi]     : b2f(((const u16*)qmask)[qi]);
        float q1 = f32io ? ((const float*)qmask)[qi + 1] : b2f(((const u16*)qmask)[qi + 1]);
        const int sidx = (q1 > q0) ? 1 : 0;   // np.argmax tie -> first index
        float sv[8];
        load8(spk, (size_t)sidx * 512 + cs, f32io, sv);
#pragma unroll
        for (int j = 0; j < 8; ++j) vals[j] += sv[j];
      }
      const size_t oidx = (size_t)u * 4608 + (size_t)mod * 1536 + cs;
      if (f32io) {
        float4* op = (float4*)((float*)outv + oidx);
        op[0] = make_float4(vals[0], vals[1], vals[2], vals[3]);
        op[1] = make_float4(vals[4], vals[5], vals[6], vals[7]);
      } else {
        store8_bf16((u16*)outv, oidx, vals);
      }
      uint32_t w[4];
#pragma unroll
      for (int p = 0; p < 4; ++p)
        w[p] = (uint32_t)f2b(vals[2 * p]) | ((uint32_t)f2b(vals[2 * p + 1]) << 16);
      *(uint4*)&Xs[(((r >> 4) * 16 + kc) << 9) + (cq * 16 + (r & 15)) * 8] =
          make_uint4(w[0], w[1], w[2], w[3]);
    }
    const int rz = 120 + rg;                 // zero pad rows 120..127
    *(uint4*)&Xs[(((rz >> 4) * 16 + kc) << 9) + (cq * 16 + (rz & 15)) * 8] =
        make_uint4(0, 0, 0, 0);
  }
  __syncthreads();

  // ---- layer 0: x1 = feats @ fc1W + fc1b ----
  f32x4 acc[8][4];
#pragma unroll
  for (int rb = 0; rb < 8; ++rb)
#pragma unroll
    for (int nb = 0; nb < 4; ++nb) {
      f32x4 z = {0.f, 0.f, 0.f, 0.f};
      acc[rb][nb] = z;
    }
  gemm_layer(acc, Xs, WtF, nt, lane);
  bias_add(acc, fc1b, 0, f32io, nt, l16);
  writeout(outv, acc, d, 512, f32io, nt, quad, l16);   // d_out x1

  // ---- 4 GCN layers: acc += agg(f2b(acc)) @ Wk + bk ----
#pragma unroll 1
  for (int L = 0; L < 4; ++L) {
    __syncthreads();                 // all waves done reading X in gemm_layer
    gb_agg(acc, Xs, nt, lane, quad, l16);   // wave-private cols: gb+colsum+agg
    __syncthreads();                 // X(agg) complete across all cols
    gemm_layer(acc, Xs, WtF + (size_t)(L + 1) * 262144, nt, lane);  // C-init = g
    bias_add(acc, convb, L * 512, f32io, nt, l16);
  }
  writeout(outv, acc, d, 1024, f32io, nt, quad, l16);  // d_out gnn_out
}

// ---------- launch ----------
extern "C" void kernel_launch(void* const* d_in, const int* in_sizes, int n_in,
                              void* d_out, int out_size, void* d_ws, size_t ws_size,
                              hipStream_t stream)
{
  const void* a     = d_in[0];
  const void* v     = d_in[1];
  const void* l     = d_in[2];
  const void* qmask = d_in[3];
  const void* spk   = d_in[4];
  const void* fc1W  = d_in[5];
  const void* fc1b  = d_in[6];
  const void* convW = d_in[7];
  const void* convb = d_in[8];

  u16* WtF = (u16*)d_ws;                     // 5*512*512*2 = 2,621,440 B

  // 1) weights -> frag-major WtF (dtype detect folded in)
  transw_k<<<dim3(16, 16, 5), dim3(32, 32), 0, stream>>>(fc1W, convW,
                                                         (const u16*)l, WtF);

  // 2) entire per-dialogue pipeline, one persistent kernel (128 blocks)
  fused_k<<<128, 512, 0, stream>>>(a, v, l, qmask, spk, fc1b, convb, WtF, d_out);
}

// Round 9
// 262.634 us; speedup vs baseline: 1.3809x; 1.0328x over previous
//
#include <hip/hip_runtime.h>
#include <cstdint>
#include <cstddef>

typedef unsigned short u16;
typedef __attribute__((ext_vector_type(8))) short bf16x8;
typedef __attribute__((ext_vector_type(4))) float f32x4;

// ---------- bf16 helpers ----------
__device__ __forceinline__ float b2f(u16 u) {
  union { uint32_t i; float f; } x; x.i = ((uint32_t)u) << 16; return x.f;
}
__device__ __forceinline__ u16 f2b(float f) {
  union { float f; uint32_t i; } x; x.f = f;
  uint32_t u = x.i;
  u += 0x7fffu + ((u >> 16) & 1u);   // RNE
  return (u16)(u >> 16);
}
__device__ __forceinline__ void load8(const void* p, size_t idx, bool f32, float o[8]) {
  if (f32) {
    const float4* fp = (const float4*)((const float*)p + idx);
    float4 x = fp[0], y = fp[1];
    o[0] = x.x; o[1] = x.y; o[2] = x.z; o[3] = x.w;
    o[4] = y.x; o[5] = y.y; o[6] = y.z; o[7] = y.w;
  } else {
    uint4 w = *(const uint4*)((const u16*)p + idx);
    uint32_t ww[4] = {w.x, w.y, w.z, w.w};
#pragma unroll
    for (int q = 0; q < 4; q++) {
      o[2 * q]     = b2f((u16)(ww[q] & 0xffffu));
      o[2 * q + 1] = b2f((u16)(ww[q] >> 16));
    }
  }
}
__device__ __forceinline__ void store8_bf16(u16* p, size_t idx, const float o[8]) {
  uint32_t w[4];
#pragma unroll
  for (int q = 0; q < 4; q++)
    w[q] = (uint32_t)f2b(o[2 * q]) | ((uint32_t)f2b(o[2 * q + 1]) << 16);
  *(uint4*)(p + idx) = make_uint4(w[0], w[1], w[2], w[3]);
}

// per-block dtype detect (bf16 vs f32) from raw bits of l; broadcast via LDS.
__device__ __forceinline__ bool detect_f32(const u16* lb, int* ldsflag, int tid) {
  if (tid < 64) {
    int bad = 0;
    for (int i = tid; i < 1024; i += 64) {
      float f = b2f(lb[i]);
      if (!(fabsf(f) <= 1.0e4f)) bad = 1;   // catches NaN too
    }
    int any = __any(bad);
    if (tid == 0) *ldsflag = any;
  }
  __syncthreads();
  const bool r = (*ldsflag != 0);
  __syncthreads();
  return r;
}

// ================= fragment-major layouts (as r6/r7, verified passing) =======
// elem (row, k): chunk = (row>>4)*16 + (k>>5); off_u16 = chunk*512 +
//   (((k>>3)&3)*16 + (row&15))*8 + (k&7).
// A wave's fragment (rb, kb) = base + lane*8 -> one coalesced 16B/lane access
// (lane = q*16+l16 : row = rb*16+l16, k = kb*32+q*8+e). Same for W with n.

// ---------- weight transpose -> frag-major WtF (verbatim from r6) ----------
__global__ __launch_bounds__(1024)
void transw_k(const void* __restrict__ fc1W, const void* __restrict__ convW,
              const u16* __restrict__ lbits, u16* __restrict__ WtF)
{
  __shared__ u16 tile[32][33];
  __shared__ int flagS;
  const int tx = threadIdx.x, ty = threadIdx.y;
  const int tid = ty * 32 + tx;
  const bool f32 = detect_f32(lbits, &flagS, tid);
  const int w = blockIdx.z;
  const void* W = (w == 0) ? fc1W : convW;
  const size_t base = (w == 0) ? 0 : (size_t)(w - 1) * 262144;
  const int bx = blockIdx.x, by = blockIdx.y;
  const size_t i = base + (size_t)(by * 32 + ty) * 512 + (bx * 32 + tx);
  float val = f32 ? ((const float*)W)[i] : b2f(((const u16*)W)[i]);
  tile[ty][tx] = f2b(val);   // tile[ty][tx] = W[by*32+ty][bx*32+tx]
  __syncthreads();
  // output: n = bx*32 + nbp*16 + l16 ; k = by*32 + q*8 + e ; value = W[k][n]
  const int e = tid & 7, l16 = (tid >> 3) & 15, q = (tid >> 7) & 3, nbp = tid >> 9;
  const u16 vv = tile[q * 8 + e][nbp * 16 + l16];
  WtF[(size_t)w * 262144 + ((size_t)((bx * 2 + nbp) * 16 + by)) * 512 +
      (q * 16 + l16) * 8 + e] = vv;
}

// ---------- persistent per-dialogue fused kernel ----------
// 128 blocks (1/dialogue) x 512 thr (8 waves). X (120x512 bf16 + pad rows) lives
// in LDS frag-major (131072 B). Wave w owns output cols [w*64, w*64+64):
// acc[8][4] f32x4 = running residual g (never leaves registers). W fragments are
// read straight from global (L2-resident, 1KB/frag coalesced, 1-deep prefetch)
// -> ZERO barriers inside the K-loop. gb+colsum+agg are column-local per wave.
// Writeouts stage through Xs-as-f32-scratch (X is dead at both writeout points;
// pad-row garbage only ever reaches acc rows >=120, which are never observed)
// so every global store is a wide, fully-coalesced float4/uint4.

__device__ __forceinline__ void gemm_layer(f32x4 (&acc)[8][4], const u16* Xs,
                                           const u16* __restrict__ WL,
                                           int nt, int lane)
{
  const int lane8 = lane * 8;
  bf16x8 cw[4], nw[4];
#pragma unroll
  for (int nb = 0; nb < 4; ++nb)
    cw[nb] = *(const bf16x8*)(WL + (((nt * 4 + nb) * 16) << 9) + lane8);
#pragma unroll 2
  for (int kb = 0; kb < 16; ++kb) {
    if (kb < 15) {
#pragma unroll
      for (int nb = 0; nb < 4; ++nb)
        nw[nb] = *(const bf16x8*)(WL + (((nt * 4 + nb) * 16 + kb + 1) << 9) + lane8);
    }
    bf16x8 af[4];
#pragma unroll
    for (int rb = 0; rb < 4; ++rb)
      af[rb] = *(const bf16x8*)&Xs[((rb * 16 + kb) << 9) + lane8];
    __builtin_amdgcn_s_setprio(1);
#pragma unroll
    for (int rb = 0; rb < 4; ++rb)
#pragma unroll
      for (int nb = 0; nb < 4; ++nb)
        acc[rb][nb] = __builtin_amdgcn_mfma_f32_16x16x32_bf16(af[rb], cw[nb],
                                                              acc[rb][nb], 0, 0, 0);
    __builtin_amdgcn_s_setprio(0);
#pragma unroll
    for (int rb = 4; rb < 8; ++rb)
      af[rb - 4] = *(const bf16x8*)&Xs[((rb * 16 + kb) << 9) + lane8];
    __builtin_amdgcn_s_setprio(1);
#pragma unroll
    for (int rb = 4; rb < 8; ++rb)
#pragma unroll
      for (int nb = 0; nb < 4; ++nb)
        acc[rb][nb] = __builtin_amdgcn_mfma_f32_16x16x32_bf16(af[rb - 4], cw[nb],
                                                              acc[rb][nb], 0, 0, 0);
    __builtin_amdgcn_s_setprio(0);
#pragma unroll
    for (int nb = 0; nb < 4; ++nb) cw[nb] = nw[nb];
  }
}

__device__ __forceinline__ void bias_add(f32x4 (&acc)[8][4], const void* bptr,
                                         int boff, bool f32io, int nt, int l16)
{
#pragma unroll
  for (int nb = 0; nb < 4; ++nb) {
    const int col = nt * 64 + nb * 16 + l16;
    const float b = f32io ? ((const float*)bptr)[boff + col]
                          : b2f(((const u16*)bptr)[boff + col]);
#pragma unroll
    for (int rb = 0; rb < 8; ++rb)
#pragma unroll
      for (int r = 0; r < 4; ++r) acc[rb][nb][r] += b;
  }
}

// ---- coalesced writeout: acc -> LDS f32 scratch (3 passes of 40 rows = one
// modality block each) -> wide global stores. S aliases Xs (dead at call time).
__device__ __forceinline__ void writeout_co(void* outv, const f32x4 (&acc)[8][4],
                                            float* S, int d, int cbase, bool f32io,
                                            int nt, int quad, int l16, int tid)
{
  const int rg = tid >> 6;          // 0..7
  const int cs = (tid & 63) * 8;    // col base for the read phase
#pragma unroll
  for (int p = 0; p < 3; ++p) {
    const int p0 = p * 40;
    __syncthreads();                // X reads / previous-pass reads complete
#pragma unroll
    for (int rb = 0; rb < 8; ++rb)
#pragma unroll
      for (int r = 0; r < 4; ++r) {
        const int row = rb * 16 + quad * 4 + r;
        const int lr = row - p0;
        if (lr >= 0 && lr < 40) {
#pragma unroll
          for (int nb = 0; nb < 4; ++nb)
            S[lr * 516 + nt * 64 + nb * 16 + l16] = acc[rb][nb][r];
        }
      }
    __syncthreads();
    // read+store: 5 iters x 8 rows; per row, 64 lanes cover 512 contiguous cols
#pragma unroll
    for (int it = 0; it < 5; ++it) {
      const int lr = it * 8 + rg;   // 0..39 ; t = lr, mod = p
      const size_t ob = (size_t)(d * 40 + lr) * 4608 + (size_t)p * 1536 + cbase + cs;
      const float* sp = &S[lr * 516 + cs];
      if (f32io) {
        float4 v0 = *(const float4*)sp, v1 = *(const float4*)(sp + 4);
        float* op = (float*)outv + ob;
        *(float4*)op = v0; *(float4*)(op + 4) = v1;
      } else {
        float vals[8];
#pragma unroll
        for (int q2 = 0; q2 < 8; ++q2) vals[q2] = sp[q2];
        store8_bf16((u16*)outv, ob, vals);
      }
    }
  }
}

// gb = f2b(acc) into this wave's 64 cols of X, then colsum (t-ascending) + agg
// in place -- entirely column-local to the wave, no cross-wave sync needed.
__device__ __forceinline__ void gb_agg(const f32x4 (&acc)[8][4], u16* Xs,
                                       int nt, int lane, int quad, int l16)
{
#pragma unroll
  for (int nb = 0; nb < 4; ++nb) {
    const int c = nt * 64 + nb * 16 + l16;
    const int kc = c >> 5, cq = (c >> 3) & 3, e = c & 7;
#pragma unroll
    for (int rb = 0; rb < 8; ++rb)
#pragma unroll
      for (int r = 0; r < 4; ++r) {
        const int row = rb * 16 + quad * 4 + r;
        if (row < 120)
          Xs[((rb * 16 + kc) << 9) + (cq * 16 + (row & 15)) * 8 + e] =
              f2b(acc[rb][nb][r]);
      }
  }
  asm volatile("s_waitcnt lgkmcnt(0)" ::: "memory");   // writes -> reads below
  const int c = nt * 64 + lane;                        // lane-private column
  const int kc = c >> 5, cq = (c >> 3) & 3, e = c & 7;
  float bs[3];
#pragma unroll
  for (int m = 0; m < 3; ++m) {
    float s = 0.f;
#pragma unroll 8
    for (int t = 0; t < 40; ++t) {
      const int row = m * 40 + t;
      s += b2f(Xs[(((row >> 4) * 16 + kc) << 9) + (cq * 16 + (row & 15)) * 8 + e]);
    }
    bs[m] = s;
  }
  const float inv42 = 1.0f / 42.0f;
#pragma unroll 4
  for (int t = 0; t < 40; ++t) {
    const int r0 = t, r1 = 40 + t, r2 = 80 + t;
    const int i0 = (((r0 >> 4) * 16 + kc) << 9) + (cq * 16 + (r0 & 15)) * 8 + e;
    const int i1 = (((r1 >> 4) * 16 + kc) << 9) + (cq * 16 + (r1 & 15)) * 8 + e;
    const int i2 = (((r2 >> 4) * 16 + kc) << 9) + (cq * 16 + (r2 & 15)) * 8 + e;
    const float x0 = b2f(Xs[i0]), x1 = b2f(Xs[i1]), x2 = b2f(Xs[i2]);
    Xs[i0] = f2b((bs[0] + x1 + x2) * inv42);
    Xs[i1] = f2b((bs[1] + x0 + x2) * inv42);
    Xs[i2] = f2b((bs[2] + x0 + x1) * inv42);
  }
}

__global__ __launch_bounds__(512, 2)
void fused_k(const void* __restrict__ a, const void* __restrict__ v,
             const void* __restrict__ l, const void* __restrict__ qmask,
             const void* __restrict__ spk, const void* __restrict__ fc1b,
             const void* __restrict__ convb, const u16* __restrict__ WtF,
             void* __restrict__ outv)
{
  __shared__ __align__(16) u16 Xs[65536];   // 131072 B, frag-major X / f32 scratch
  __shared__ int flagS;
  const int tid = threadIdx.x;
  const bool f32io = detect_f32((const u16*)l, &flagS, tid);
  const int d = blockIdx.x;
  const int lane = tid & 63, nt = tid >> 6;
  const int quad = lane >> 4, l16 = lane & 15;

  // ---- feats phase: inputs -> d_out cols [0,512) + X (bf16 frag) ----
  {
    const int cs = (tid & 63) * 8;
    const int rg = tid >> 6;
    const int kc = cs >> 5, cq = (cs >> 3) & 3;
#pragma unroll
    for (int it = 0; it < 15; ++it) {
      const int r = it * 8 + rg;            // 0..119
      const int mod = r / 40, t = r - mod * 40;
      const int u = d * 40 + t;
      float vals[8];
      const void* srcp = (mod == 1) ? a : ((mod == 2) ? v : l);
      load8(srcp, (size_t)u * 512 + cs, f32io, vals);
      if (mod == 0) {
        const int qi = (t * 128 + d) * 2;
        float q0 = f32io ? ((const float*)qmask)[qi]     : b2f(((const u16*)qmask)[qi]);
        float q1 = f32io ? ((const float*)qmask)[qi + 1] : b2f(((const u16*)qmask)[qi + 1]);
        const int sidx = (q1 > q0) ? 1 : 0;   // np.argmax tie -> first index
        float sv[8];
        load8(spk, (size_t)sidx * 512 + cs, f32io, sv);
#pragma unroll
        for (int j = 0; j < 8; ++j) vals[j] += sv[j];
      }
      const size_t oidx = (size_t)u * 4608 + (size_t)mod * 1536 + cs;
      if (f32io) {
        float4* op = (float4*)((float*)outv + oidx);
        op[0] = make_float4(vals[0], vals[1], vals[2], vals[3]);
        op[1] = make_float4(vals[4], vals[5], vals[6], vals[7]);
      } else {
        store8_bf16((u16*)outv, oidx, vals);
      }
      uint32_t w[4];
#pragma unroll
      for (int p = 0; p < 4; ++p)
        w[p] = (uint32_t)f2b(vals[2 * p]) | ((uint32_t)f2b(vals[2 * p + 1]) << 16);
      *(uint4*)&Xs[(((r >> 4) * 16 + kc) << 9) + (cq * 16 + (r & 15)) * 8] =
          make_uint4(w[0], w[1], w[2], w[3]);
    }
    const int rz = 120 + rg;                 // zero pad rows 120..127
    *(uint4*)&Xs[(((rz >> 4) * 16 + kc) << 9) + (cq * 16 + (rz & 15)) * 8] =
        make_uint4(0, 0, 0, 0);
  }
  __syncthreads();

  // ---- layer 0: x1 = feats @ fc1W + fc1b ----
  f32x4 acc[8][4];
#pragma unroll
  for (int rb = 0; rb < 8; ++rb)
#pragma unroll
    for (int nb = 0; nb < 4; ++nb) {
      f32x4 z = {0.f, 0.f, 0.f, 0.f};
      acc[rb][nb] = z;
    }
  gemm_layer(acc, Xs, WtF, nt, lane);
  bias_add(acc, fc1b, 0, f32io, nt, l16);
  // x1 -> d_out cols [512,1024); X(feats) is dead -> Xs doubles as f32 scratch
  writeout_co(outv, acc, (float*)Xs, d, 512, f32io, nt, quad, l16, tid);

  // ---- 4 GCN layers: acc += agg(f2b(acc)) @ Wk + bk ----
#pragma unroll 1
  for (int L = 0; L < 4; ++L) {
    __syncthreads();                 // scratch/X reads complete before overwrite
    gb_agg(acc, Xs, nt, lane, quad, l16);   // wave-private cols: gb+colsum+agg
    __syncthreads();                 // X(agg) complete across all cols
    gemm_layer(acc, Xs, WtF + (size_t)(L + 1) * 262144, nt, lane);  // C-init = g
    bias_add(acc, convb, L * 512, f32io, nt, l16);
  }
  // gnn_out -> d_out cols [1024,1536); X dead again
  writeout_co(outv, acc, (float*)Xs, d, 1024, f32io, nt, quad, l16, tid);
}

// ---------- launch ----------
extern "C" void kernel_launch(void* const* d_in, const int* in_sizes, int n_in,
                              void* d_out, int out_size, void* d_ws, size_t ws_size,
                              hipStream_t stream)
{
  const void* a     = d_in[0];
  const void* v     = d_in[1];
  const void* l     = d_in[2];
  const void* qmask = d_in[3];
  const void* spk   = d_in[4];
  const void* fc1W  = d_in[5];
  const void* fc1b  = d_in[6];
  const void* convW = d_in[7];
  const void* convb = d_in[8];

  u16* WtF = (u16*)d_ws;                     // 5*512*512*2 = 2,621,440 B

  // 1) weights -> frag-major WtF (dtype detect folded in)
  transw_k<<<dim3(16, 16, 5), dim3(32, 32), 0, stream>>>(fc1W, convW,
                                                         (const u16*)l, WtF);

  // 2) entire per-dialogue pipeline, one persistent kernel (128 blocks)
  fused_k<<<128, 512, 0, stream>>>(a, v, l, qmask, spk, fc1b, convb, WtF, d_out);
}